// Round 11
// baseline (99.167 us; speedup 1.0000x reference)
//
#include <hip/hip_runtime.h>
#include <hip/hip_fp16.h>

// B=4, S=512, D=256, UNITS=128. out: [B,S,D] fp32.
#define SEQ 512
#define DIM 256
#define UN  128
#define BSZ 2048                       // B*S
#define CSC 2.8853900817779268f        // 2*log2(e)

typedef _Float16 half8 __attribute__((ext_vector_type(8)));
typedef float   float4v __attribute__((ext_vector_type(4)));
struct h4s { __half2 a, b; };          // 8B = 4 f16

static __device__ __forceinline__ unsigned short f2bf(float x) {  // RNE, x>0 finite
  unsigned u = __float_as_uint(x);
  u += 0x7FFF + ((u >> 16) & 1);
  return (unsigned short)(u >> 16);
}
static __device__ __forceinline__ float bf2f(unsigned short s) {
  return __uint_as_float((unsigned)s << 16);
}

// ---- proj: Eq = exp2(CSC*(values@Wq)) [BSZ][UN] fp32,
//            Ev = bf16(exp2(CSC*(values@Wv)))^T [UN][BSZ],
//            Vt = f16(values)^T [DIM][BSZ]  (B-operand layout for MFMA ctx)
__global__ __launch_bounds__(256) void proj_kernel(
    const float* __restrict__ values, const float* __restrict__ Wq,
    const float* __restrict__ Wv, float* __restrict__ Eq,
    unsigned short* __restrict__ Ev, _Float16* __restrict__ Vt) {
  __shared__ float vsm[4 * DIM];
  const int t = threadIdx.x;
  const int r0 = blockIdx.x * 4;
  {
    const int row = t >> 6, c4 = (t & 63) * 4;
    const float4 v = *(const float4*)(values + (r0 + row) * DIM + c4);
    *(float4*)&vsm[row * DIM + c4] = v;
  }
  __syncthreads();
  // transposed f16 write: thread t owns column d=t, 4 rows -> 8B store
  {
    h4s o;
    o.a = __floats2half2_rn(vsm[0 * DIM + t], vsm[1 * DIM + t]);
    o.b = __floats2half2_rn(vsm[2 * DIM + t], vsm[3 * DIM + t]);
    *(h4s*)(Vt + (size_t)t * BSZ + r0) = o;
  }
  const int half = t >> 7, u = t & 127;
  const float* __restrict__ W = half ? Wv : Wq;
  float acc[4] = {0.f, 0.f, 0.f, 0.f};
  for (int d = 0; d < DIM; d += 4) {
    const float w0 = W[(d + 0) * UN + u], w1 = W[(d + 1) * UN + u];
    const float w2 = W[(d + 2) * UN + u], w3 = W[(d + 3) * UN + u];
#pragma unroll
    for (int k = 0; k < 4; ++k) {
      const float4 v = *(const float4*)&vsm[k * DIM + d];
      acc[k] = fmaf(v.x, w0, acc[k]);
      acc[k] = fmaf(v.y, w1, acc[k]);
      acc[k] = fmaf(v.z, w2, acc[k]);
      acc[k] = fmaf(v.w, w3, acc[k]);
    }
  }
  if (!half) {
#pragma unroll
    for (int k = 0; k < 4; ++k)
      Eq[(r0 + k) * UN + u] = __builtin_amdgcn_exp2f(acc[k] * CSC);
  } else {
    ushort4 o;
    o.x = f2bf(__builtin_amdgcn_exp2f(acc[0] * CSC));
    o.y = f2bf(__builtin_amdgcn_exp2f(acc[1] * CSC));
    o.z = f2bf(__builtin_amdgcn_exp2f(acc[2] * CSC));
    o.w = f2bf(__builtin_amdgcn_exp2f(acc[3] * CSC));
    *(ushort4*)(Ev + (size_t)u * BSZ + r0) = o;   // 8B aligned
  }
}

// ---- score: block = (b, pair p), rows {p, 511-p}. r10 structure; phase A now:
//  (1) paired-rcp: 1/a,1/b from one rcp(a*b)  -> half the trans ops
//  (2) wave roles flipped per block (tt = t ^ hash<<6) -> SIMD load balance
__global__ __launch_bounds__(256, 4) void score_kernel(
    const float* __restrict__ Eq, const unsigned short* __restrict__ Ev,
    const float* __restrict__ Vw, _Float16* __restrict__ P) {
  __shared__ float sc[2 * SEQ];     // u-half-0 sdot -> probs. [lo | hi]
  __shared__ float scp[2 * SEQ];    // u-half-1 sdot partials
  __shared__ float invs[2];

  const int t = threadIdx.x;
  const int x = blockIdx.x;
  const int b = x >> 8, p = x & 255;
  const int bS = b * SEQ;
  const int i = p;                  // low row: j in [0, i], i <= 255
  const int ihi = SEQ - 1 - p;      // high row: j in [0, jhi], jhi >= 256
  const int jhi = ihi;

  const float* __restrict__ eql = Eq + (size_t)(bS + i) * UN;    // uniform -> s_load
  const float* __restrict__ eqh = Eq + (size_t)(bS + ihi) * UN;

  // ---- phase A: thread owns j-quad (8B bf16 Ev load) x u-half; depth-4 prefetch ----
  {
    const int flip = ((x ^ (x >> 1) ^ (x >> 8)) & 1) << 6;  // SIMD de-skew
    const int tt = t ^ flip;
    const int qd = tt & 127, jb = qd << 2;
    const int u0 = (tt >> 7) << 6;
    float* __restrict__ so = (tt >> 7) ? scp : sc;
    const unsigned short* __restrict__ evp = Ev + (size_t)u0 * BSZ + bS + jb;
#define LDE(K) (*(const ushort4*)(evp + (size_t)(K) * BSZ))
    if ((tt & 64) == 0) {           // dual-row waves: jb < 256
      float h0=0.f,h1=0.f,h2=0.f,h3=0.f,l0=0.f,l1=0.f,l2=0.f,l3=0.f;
      ushort4 e0 = LDE(0), e1 = LDE(1), e2 = LDE(2), e3 = LDE(3);
      // per (u,j): a=1+ql*e, b=1+qh*e; r=rcp(a*b); s=w*r; lo+=s*b; hi+=s*a
#define PRD(EC, KK) { \
      const float qh = eqh[u0 + (KK)], ql = eql[u0 + (KK)], ww = Vw[u0 + (KK)]; \
      const float f0 = bf2f(EC.x), f1 = bf2f(EC.y), f2 = bf2f(EC.z), f3 = bf2f(EC.w); \
      const float a0 = fmaf(ql, f0, 1.f), b0 = fmaf(qh, f0, 1.f); \
      const float a1 = fmaf(ql, f1, 1.f), b1 = fmaf(qh, f1, 1.f); \
      const float a2 = fmaf(ql, f2, 1.f), b2 = fmaf(qh, f2, 1.f); \
      const float a3 = fmaf(ql, f3, 1.f), b3 = fmaf(qh, f3, 1.f); \
      const float s0 = ww * __builtin_amdgcn_rcpf(a0 * b0); \
      const float s1 = ww * __builtin_amdgcn_rcpf(a1 * b1); \
      const float s2 = ww * __builtin_amdgcn_rcpf(a2 * b2); \
      const float s3 = ww * __builtin_amdgcn_rcpf(a3 * b3); \
      l0 = fmaf(s0, b0, l0); h0 = fmaf(s0, a0, h0); \
      l1 = fmaf(s1, b1, l1); h1 = fmaf(s1, a1, h1); \
      l2 = fmaf(s2, b2, l2); h2 = fmaf(s2, a2, h2); \
      l3 = fmaf(s3, b3, l3); h3 = fmaf(s3, a3, h3); }
      for (int k = 0; k < 64; k += 4) {
        // prefetch overshoot (<= Ev row 131) lands in Vt ws region: valid memory
        ushort4 n;
        n = LDE(k + 4); PRD(e0, k + 0); e0 = n;
        n = LDE(k + 5); PRD(e1, k + 1); e1 = n;
        n = LDE(k + 6); PRD(e2, k + 2); e2 = n;
        n = LDE(k + 7); PRD(e3, k + 3); e3 = n;
      }
#undef PRD
      *(float4*)&so[SEQ + jb] = make_float4(h0, h1, h2, h3);
      *(float4*)&so[jb]       = make_float4(l0, l1, l2, l3);
    } else if (jb <= jhi) {         // single-row waves: jb >= 256, hi only
      float h0=0.f,h1=0.f,h2=0.f,h3=0.f;
      ushort4 e0 = LDE(0), e1 = LDE(1), e2 = LDE(2), e3 = LDE(3);
      // pair adjacent j: r=rcp(a*b) serves both
#define PRS(EC, KK) { \
      const float q = eqh[u0 + (KK)], ww = Vw[u0 + (KK)]; \
      const float f0 = bf2f(EC.x), f1 = bf2f(EC.y), f2 = bf2f(EC.z), f3 = bf2f(EC.w); \
      const float a = fmaf(q, f0, 1.f), bb = fmaf(q, f1, 1.f); \
      const float c = fmaf(q, f2, 1.f), d  = fmaf(q, f3, 1.f); \
      const float sA = ww * __builtin_amdgcn_rcpf(a * bb); \
      const float sB = ww * __builtin_amdgcn_rcpf(c * d); \
      h0 = fmaf(sA, bb, h0); h1 = fmaf(sA, a, h1); \
      h2 = fmaf(sB, d,  h2); h3 = fmaf(sB, c, h3); }
      for (int k = 0; k < 64; k += 4) {
        ushort4 n;
        n = LDE(k + 4); PRS(e0, k + 0); e0 = n;
        n = LDE(k + 5); PRS(e1, k + 1); e1 = n;
        n = LDE(k + 6); PRS(e2, k + 2); e2 = n;
        n = LDE(k + 7); PRS(e3, k + 3); e3 = n;
      }
#undef PRS
      *(float4*)&so[SEQ + jb] = make_float4(h0, h1, h2, h3);
    }
#undef LDE
  }
  __syncthreads();

  // ---- phase B: softmax, wave0 -> low row, wave1 -> high row ----
  {
    const int w = t >> 6, l = t & 63;
    if (w < 2) {
      const int jmax = (w == 0) ? i : jhi;
      float* __restrict__ r0p = sc + w * SEQ;
      const float* __restrict__ r1p = scp + w * SEQ;
      float m = 1e30f;                           // min sdot == max score
      for (int j = l; j <= jmax; j += 64) m = fminf(m, r0p[j] + r1p[j]);
#pragma unroll
      for (int o = 32; o; o >>= 1) m = fminf(m, __shfl_xor(m, o));
      float sum = 0.f;
      for (int j = l; j <= jmax; j += 64) {
        const float pr = __builtin_amdgcn_exp2f((m - (r0p[j] + r1p[j])) * CSC);
        r0p[j] = pr;
        sum += pr;
      }
#pragma unroll
      for (int o = 32; o; o >>= 1) sum += __shfl_xor(sum, o);
      if (l == 0) invs[w] = __builtin_amdgcn_rcpf(sum);
    }
  }
  __syncthreads();

  // ---- epilogue: normalized f16 P with explicit zeros in every masked slot ----
  {
    const float invLo = invs[0], invHi = invs[1];
    const int t2 = t + 256;
    const float pLo = (t <= i) ? sc[t] * invLo : 0.f;          // lo cols [0,256)
    const float pHa = sc[SEQ + t] * invHi;                      // t <= 255 <= jhi
    const float pHb = (t2 <= jhi) ? sc[SEQ + t2] * invHi : 0.f; // hi cols [256,512)
    P[(size_t)(bS + i) * SEQ + t]    = (_Float16)pLo;
    P[(size_t)(bS + ihi) * SEQ + t]  = (_Float16)pHa;
    P[(size_t)(bS + ihi) * SEQ + t2] = (_Float16)pHb;
  }
}

// ---- ctx: out = P @ values via MFMA 16x16x32 f16 (r10, unchanged).
__global__ __launch_bounds__(256) void ctx_kernel(
    const _Float16* __restrict__ P, const _Float16* __restrict__ Vt,
    float* __restrict__ out) {
  const int t = threadIdx.x, lane = t & 63, g = t >> 6;
  const int x = blockIdx.x;
  const int b = x >> 7, ri = (x >> 2) & 31, cg = x & 3;
  const int bS = b * SEQ;
  const int d0 = cg * 64 + g * 16;
  const int m = lane & 15, q = lane >> 4;
  const int Kmax = 16 * ri + 16;                 // causal cap for this row tile

  const _Float16* __restrict__ pA = P  + (size_t)(bS + 16 * ri + m) * SEQ + q * 8;
  const _Float16* __restrict__ pB = Vt + (size_t)(d0 + m) * BSZ + bS + q * 8;
  float4v acc = {0.f, 0.f, 0.f, 0.f};
  for (int k0 = 0; k0 < Kmax; k0 += 32) {
    const half8 a  = *(const half8*)(pA + k0);
    const half8 bv = *(const half8*)(pB + k0);
    acc = __builtin_amdgcn_mfma_f32_16x16x32_f16(a, bv, acc, 0, 0, 0);
  }
  float* __restrict__ o = out + (size_t)(bS + 16 * ri + q * 4) * DIM + d0 + m;
#pragma unroll
  for (int r = 0; r < 4; ++r) o[(size_t)r * DIM] = acc[r];
}

extern "C" void kernel_launch(void* const* d_in, const int* in_sizes, int n_in,
                              void* d_out, int out_size, void* d_ws, size_t ws_size,
                              hipStream_t stream) {
  const float* values = (const float*)d_in[0];
  const float* Wq     = (const float*)d_in[1];
  const float* Wv     = (const float*)d_in[2];
  const float* Vw     = (const float*)d_in[3];
  float* out = (float*)d_out;
  float* Eq = (float*)d_ws;                                       // 1 MB
  unsigned short* Ev = (unsigned short*)(Eq + (size_t)BSZ * UN);  // 512 KB
  _Float16* Vt = (_Float16*)(Ev + (size_t)UN * BSZ);              // [DIM][BSZ] 1 MB
  _Float16* P  = Vt + (size_t)DIM * BSZ;                          // [BSZ][SEQ] 2 MB
  proj_kernel<<<dim3(BSZ / 4), 256, 0, stream>>>(values, Wq, Wv, Eq, Ev, Vt);
  score_kernel<<<dim3(4 * 256), 256, 0, stream>>>(Eq, Ev, Vw, P);
  ctx_kernel<<<dim3(4 * 32 * 4), 256, 0, stream>>>(P, Vt, out);
}

// Round 12
// 98.971 us; speedup vs baseline: 1.0020x; 1.0020x over previous
//
#include <hip/hip_runtime.h>
#include <hip/hip_fp16.h>

// B=4, S=512, D=256, UNITS=128. out: [B,S,D] fp32.
#define SEQ 512
#define DIM 256
#define UN  128
#define BSZ 2048                       // B*S
#define CSC 2.8853900817779268f        // 2*log2(e)
// L2 channels interleave at 256B; 4096B strides hit one channel set (camping).
// Pad column strides so consecutive rows shift channels:
#define EVS 2176                       // Ev row stride: 4352B = 17*256 -> +1 chan/row
#define VTS 2176                       // Vt row stride: 4352B
#define PS  640                        // P  row stride: 1280B = 5*256 -> +5 chan/row

typedef _Float16 half8 __attribute__((ext_vector_type(8)));
typedef float   float4v __attribute__((ext_vector_type(4)));
struct h4s { __half2 a, b; };          // 8B = 4 f16

static __device__ __forceinline__ unsigned short f2bf(float x) {  // RNE, x>0 finite
  unsigned u = __float_as_uint(x);
  u += 0x7FFF + ((u >> 16) & 1);
  return (unsigned short)(u >> 16);
}
static __device__ __forceinline__ float bf2f(unsigned short s) {
  return __uint_as_float((unsigned)s << 16);
}

// ---- proj: Eq = exp2(CSC*(values@Wq)) [BSZ][UN] fp32,
//            Ev = bf16(exp2(CSC*(values@Wv)))^T [UN rows, stride EVS],
//            Vt = f16(values)^T [DIM rows, stride VTS]
__global__ __launch_bounds__(256) void proj_kernel(
    const float* __restrict__ values, const float* __restrict__ Wq,
    const float* __restrict__ Wv, float* __restrict__ Eq,
    unsigned short* __restrict__ Ev, _Float16* __restrict__ Vt) {
  __shared__ float vsm[4 * DIM];
  const int t = threadIdx.x;
  const int r0 = blockIdx.x * 4;
  {
    const int row = t >> 6, c4 = (t & 63) * 4;
    const float4 v = *(const float4*)(values + (r0 + row) * DIM + c4);
    *(float4*)&vsm[row * DIM + c4] = v;
  }
  __syncthreads();
  // transposed f16 write: thread t owns column d=t, 4 rows -> 8B store
  {
    h4s o;
    o.a = __floats2half2_rn(vsm[0 * DIM + t], vsm[1 * DIM + t]);
    o.b = __floats2half2_rn(vsm[2 * DIM + t], vsm[3 * DIM + t]);
    *(h4s*)(Vt + (size_t)t * VTS + r0) = o;
  }
  const int half = t >> 7, u = t & 127;
  const float* __restrict__ W = half ? Wv : Wq;
  float acc[4] = {0.f, 0.f, 0.f, 0.f};
  for (int d = 0; d < DIM; d += 4) {
    const float w0 = W[(d + 0) * UN + u], w1 = W[(d + 1) * UN + u];
    const float w2 = W[(d + 2) * UN + u], w3 = W[(d + 3) * UN + u];
#pragma unroll
    for (int k = 0; k < 4; ++k) {
      const float4 v = *(const float4*)&vsm[k * DIM + d];
      acc[k] = fmaf(v.x, w0, acc[k]);
      acc[k] = fmaf(v.y, w1, acc[k]);
      acc[k] = fmaf(v.z, w2, acc[k]);
      acc[k] = fmaf(v.w, w3, acc[k]);
    }
  }
  if (!half) {
#pragma unroll
    for (int k = 0; k < 4; ++k)
      Eq[(r0 + k) * UN + u] = __builtin_amdgcn_exp2f(acc[k] * CSC);
  } else {
    ushort4 o;
    o.x = f2bf(__builtin_amdgcn_exp2f(acc[0] * CSC));
    o.y = f2bf(__builtin_amdgcn_exp2f(acc[1] * CSC));
    o.z = f2bf(__builtin_amdgcn_exp2f(acc[2] * CSC));
    o.w = f2bf(__builtin_amdgcn_exp2f(acc[3] * CSC));
    *(ushort4*)(Ev + (size_t)u * EVS + r0) = o;   // 8B aligned
  }
}

// ---- score: block = (b, pair p), rows {p, 511-p}. r11 code; only strides changed.
__global__ __launch_bounds__(256, 4) void score_kernel(
    const float* __restrict__ Eq, const unsigned short* __restrict__ Ev,
    const float* __restrict__ Vw, _Float16* __restrict__ P) {
  __shared__ float sc[2 * SEQ];     // u-half-0 sdot -> probs. [lo | hi]
  __shared__ float scp[2 * SEQ];    // u-half-1 sdot partials
  __shared__ float invs[2];

  const int t = threadIdx.x;
  const int x = blockIdx.x;
  const int b = x >> 8, p = x & 255;
  const int bS = b * SEQ;
  const int i = p;                  // low row: j in [0, i], i <= 255
  const int ihi = SEQ - 1 - p;      // high row: j in [0, jhi], jhi >= 256
  const int jhi = ihi;

  const float* __restrict__ eql = Eq + (size_t)(bS + i) * UN;    // uniform -> s_load
  const float* __restrict__ eqh = Eq + (size_t)(bS + ihi) * UN;

  // ---- phase A: thread owns j-quad (8B bf16 Ev load) x u-half; depth-4 prefetch ----
  {
    const int flip = ((x ^ (x >> 1) ^ (x >> 8)) & 1) << 6;  // SIMD de-skew
    const int tt = t ^ flip;
    const int qd = tt & 127, jb = qd << 2;
    const int u0 = (tt >> 7) << 6;
    float* __restrict__ so = (tt >> 7) ? scp : sc;
    const unsigned short* __restrict__ evp = Ev + (size_t)u0 * EVS + bS + jb;
#define LDE(K) (*(const ushort4*)(evp + (size_t)(K) * EVS))
    if ((tt & 64) == 0) {           // dual-row waves: jb < 256
      float h0=0.f,h1=0.f,h2=0.f,h3=0.f,l0=0.f,l1=0.f,l2=0.f,l3=0.f;
      ushort4 e0 = LDE(0), e1 = LDE(1), e2 = LDE(2), e3 = LDE(3);
      // per (u,j): a=1+ql*e, b=1+qh*e; r=rcp(a*b); s=w*r; lo+=s*b; hi+=s*a
#define PRD(EC, KK) { \
      const float qh = eqh[u0 + (KK)], ql = eql[u0 + (KK)], ww = Vw[u0 + (KK)]; \
      const float f0 = bf2f(EC.x), f1 = bf2f(EC.y), f2 = bf2f(EC.z), f3 = bf2f(EC.w); \
      const float a0 = fmaf(ql, f0, 1.f), b0 = fmaf(qh, f0, 1.f); \
      const float a1 = fmaf(ql, f1, 1.f), b1 = fmaf(qh, f1, 1.f); \
      const float a2 = fmaf(ql, f2, 1.f), b2 = fmaf(qh, f2, 1.f); \
      const float a3 = fmaf(ql, f3, 1.f), b3 = fmaf(qh, f3, 1.f); \
      const float s0 = ww * __builtin_amdgcn_rcpf(a0 * b0); \
      const float s1 = ww * __builtin_amdgcn_rcpf(a1 * b1); \
      const float s2 = ww * __builtin_amdgcn_rcpf(a2 * b2); \
      const float s3 = ww * __builtin_amdgcn_rcpf(a3 * b3); \
      l0 = fmaf(s0, b0, l0); h0 = fmaf(s0, a0, h0); \
      l1 = fmaf(s1, b1, l1); h1 = fmaf(s1, a1, h1); \
      l2 = fmaf(s2, b2, l2); h2 = fmaf(s2, a2, h2); \
      l3 = fmaf(s3, b3, l3); h3 = fmaf(s3, a3, h3); }
      for (int k = 0; k < 64; k += 4) {
        // prefetch overshoot (<= Ev row 131 < 136 alloc) stays in Ev region: valid
        ushort4 n;
        n = LDE(k + 4); PRD(e0, k + 0); e0 = n;
        n = LDE(k + 5); PRD(e1, k + 1); e1 = n;
        n = LDE(k + 6); PRD(e2, k + 2); e2 = n;
        n = LDE(k + 7); PRD(e3, k + 3); e3 = n;
      }
#undef PRD
      *(float4*)&so[SEQ + jb] = make_float4(h0, h1, h2, h3);
      *(float4*)&so[jb]       = make_float4(l0, l1, l2, l3);
    } else if (jb <= jhi) {         // single-row waves: jb >= 256, hi only
      float h0=0.f,h1=0.f,h2=0.f,h3=0.f;
      ushort4 e0 = LDE(0), e1 = LDE(1), e2 = LDE(2), e3 = LDE(3);
      // pair adjacent j: r=rcp(a*b) serves both
#define PRS(EC, KK) { \
      const float q = eqh[u0 + (KK)], ww = Vw[u0 + (KK)]; \
      const float f0 = bf2f(EC.x), f1 = bf2f(EC.y), f2 = bf2f(EC.z), f3 = bf2f(EC.w); \
      const float a = fmaf(q, f0, 1.f), bb = fmaf(q, f1, 1.f); \
      const float c = fmaf(q, f2, 1.f), d  = fmaf(q, f3, 1.f); \
      const float sA = ww * __builtin_amdgcn_rcpf(a * bb); \
      const float sB = ww * __builtin_amdgcn_rcpf(c * d); \
      h0 = fmaf(sA, bb, h0); h1 = fmaf(sA, a, h1); \
      h2 = fmaf(sB, d,  h2); h3 = fmaf(sB, c, h3); }
      for (int k = 0; k < 64; k += 4) {
        ushort4 n;
        n = LDE(k + 4); PRS(e0, k + 0); e0 = n;
        n = LDE(k + 5); PRS(e1, k + 1); e1 = n;
        n = LDE(k + 6); PRS(e2, k + 2); e2 = n;
        n = LDE(k + 7); PRS(e3, k + 3); e3 = n;
      }
#undef PRS
      *(float4*)&so[SEQ + jb] = make_float4(h0, h1, h2, h3);
    }
#undef LDE
  }
  __syncthreads();

  // ---- phase B: softmax, wave0 -> low row, wave1 -> high row ----
  {
    const int w = t >> 6, l = t & 63;
    if (w < 2) {
      const int jmax = (w == 0) ? i : jhi;
      float* __restrict__ r0p = sc + w * SEQ;
      const float* __restrict__ r1p = scp + w * SEQ;
      float m = 1e30f;                           // min sdot == max score
      for (int j = l; j <= jmax; j += 64) m = fminf(m, r0p[j] + r1p[j]);
#pragma unroll
      for (int o = 32; o; o >>= 1) m = fminf(m, __shfl_xor(m, o));
      float sum = 0.f;
      for (int j = l; j <= jmax; j += 64) {
        const float pr = __builtin_amdgcn_exp2f((m - (r0p[j] + r1p[j])) * CSC);
        r0p[j] = pr;
        sum += pr;
      }
#pragma unroll
      for (int o = 32; o; o >>= 1) sum += __shfl_xor(sum, o);
      if (l == 0) invs[w] = __builtin_amdgcn_rcpf(sum);
    }
  }
  __syncthreads();

  // ---- epilogue: normalized f16 P (stride PS) with zeros in masked slots ----
  {
    const float invLo = invs[0], invHi = invs[1];
    const int t2 = t + 256;
    const float pLo = (t <= i) ? sc[t] * invLo : 0.f;          // lo cols [0,256)
    const float pHa = sc[SEQ + t] * invHi;                      // t <= 255 <= jhi
    const float pHb = (t2 <= jhi) ? sc[SEQ + t2] * invHi : 0.f; // hi cols [256,512)
    P[(size_t)(bS + i) * PS + t]    = (_Float16)pLo;
    P[(size_t)(bS + ihi) * PS + t]  = (_Float16)pHa;
    P[(size_t)(bS + ihi) * PS + t2] = (_Float16)pHb;
  }
}

// ---- ctx: out = P @ values via MFMA 16x16x32 f16 (strides padded).
__global__ __launch_bounds__(256) void ctx_kernel(
    const _Float16* __restrict__ P, const _Float16* __restrict__ Vt,
    float* __restrict__ out) {
  const int t = threadIdx.x, lane = t & 63, g = t >> 6;
  const int x = blockIdx.x;
  const int b = x >> 7, ri = (x >> 2) & 31, cg = x & 3;
  const int bS = b * SEQ;
  const int d0 = cg * 64 + g * 16;
  const int m = lane & 15, q = lane >> 4;
  const int Kmax = 16 * ri + 16;                 // causal cap for this row tile

  const _Float16* __restrict__ pA = P  + (size_t)(bS + 16 * ri + m) * PS + q * 8;
  const _Float16* __restrict__ pB = Vt + (size_t)(d0 + m) * VTS + bS + q * 8;
  float4v acc = {0.f, 0.f, 0.f, 0.f};
  for (int k0 = 0; k0 < Kmax; k0 += 32) {
    const half8 a  = *(const half8*)(pA + k0);
    const half8 bv = *(const half8*)(pB + k0);
    acc = __builtin_amdgcn_mfma_f32_16x16x32_f16(a, bv, acc, 0, 0, 0);
  }
  float* __restrict__ o = out + (size_t)(bS + 16 * ri + q * 4) * DIM + d0 + m;
#pragma unroll
  for (int r = 0; r < 4; ++r) o[(size_t)r * DIM] = acc[r];
}

extern "C" void kernel_launch(void* const* d_in, const int* in_sizes, int n_in,
                              void* d_out, int out_size, void* d_ws, size_t ws_size,
                              hipStream_t stream) {
  const float* values = (const float*)d_in[0];
  const float* Wq     = (const float*)d_in[1];
  const float* Wv     = (const float*)d_in[2];
  const float* Vw     = (const float*)d_in[3];
  float* out = (float*)d_out;
  float* Eq = (float*)d_ws;                                       // [BSZ][UN] 1 MB
  unsigned short* Ev = (unsigned short*)(Eq + (size_t)BSZ * UN);  // 136 rows x EVS
  _Float16* Vt = (_Float16*)(Ev + (size_t)136 * EVS);             // DIM rows x VTS
  _Float16* P  = Vt + (size_t)DIM * VTS;                          // BSZ rows x PS
  proj_kernel<<<dim3(BSZ / 4), 256, 0, stream>>>(values, Wq, Wv, Eq, Ev, Vt);
  score_kernel<<<dim3(4 * 256), 256, 0, stream>>>(Eq, Ev, Vw, P);
  ctx_kernel<<<dim3(4 * 32 * 4), 256, 0, stream>>>(P, Vt, out);
}